// Round 1
// baseline (1007.831 us; speedup 1.0000x reference)
//
#include <hip/hip_runtime.h>

#define VOCAB 32000
#define EMB 64
#define NROWS 8192            // B*S = 2*4096
#define VSPLITS 25
#define VCHUNK (VOCAB / VSPLITS)   // 1280
#define VT 64                      // vocab rows per LDS tile
#define ROWS_PER_BLOCK 256

// ---------------- k1: inverse norm of each W row ----------------
__global__ void wnorm_kernel(const float* __restrict__ W, float* __restrict__ invn) {
    int v = blockIdx.x * blockDim.x + threadIdx.x;
    if (v >= VOCAB) return;
    const float4* w4 = (const float4*)(W + (size_t)v * EMB);
    float s = 0.f;
    #pragma unroll
    for (int q = 0; q < 16; ++q) {
        float4 w = w4[q];
        s += w.x * w.x + w.y * w.y + w.z * w.z + w.w * w.w;
    }
    invn[v] = 1.0f / sqrtf(s);
}

// ---------------- k2: partial argmax over a V-chunk ----------------
// grid: (NROWS/256, VSPLITS). Each thread owns one row (A row in 64 VGPRs),
// W streamed through LDS in 64-row tiles; all threads process the same v
// simultaneously -> broadcast LDS reads (conflict-free).
__global__ __launch_bounds__(256) void argmax_partial_kernel(
    const float* __restrict__ x, const float* __restrict__ W,
    const float* __restrict__ invn,
    float* __restrict__ pval, int* __restrict__ pidx)
{
    __shared__ float4 wt[VT * 16];   // 64 v x 64 d = 16 KB
    __shared__ float  invt[VT];

    const int tid = threadIdx.x;
    const int row = blockIdx.x * ROWS_PER_BLOCK + tid;
    const int v0base = blockIdx.y * VCHUNK;

    float4 a[16];
    const float4* a4 = (const float4*)(x + (size_t)row * EMB);
    #pragma unroll
    for (int q = 0; q < 16; ++q) a[q] = a4[q];

    float best = -1e30f;
    int bidx = 0;

    for (int t = 0; t < VCHUNK / VT; ++t) {
        const int v0 = v0base + t * VT;
        // cooperative coalesced tile load: 1024 float4
        const float4* wg = (const float4*)(W + (size_t)v0 * EMB);
        #pragma unroll
        for (int q = 0; q < 4; ++q)
            wt[tid + q * 256] = wg[tid + q * 256];
        if (tid < VT) invt[tid] = invn[v0 + tid];
        __syncthreads();

        for (int vv = 0; vv < VT; ++vv) {
            float s0 = 0.f, s1 = 0.f, s2 = 0.f, s3 = 0.f;
            #pragma unroll
            for (int q = 0; q < 16; ++q) {
                float4 w = wt[vv * 16 + q];
                s0 = fmaf(a[q].x, w.x, s0);
                s1 = fmaf(a[q].y, w.y, s1);
                s2 = fmaf(a[q].z, w.z, s2);
                s3 = fmaf(a[q].w, w.w, s3);
            }
            float s = ((s0 + s1) + (s2 + s3)) * invt[vv];
            // ascending v + strict '>' => keeps FIRST max index (numpy argmax)
            if (s > best) { best = s; bidx = v0 + vv; }
        }
        __syncthreads();
    }
    pval[blockIdx.y * NROWS + row] = best;
    pidx[blockIdx.y * NROWS + row] = bidx;
}

// ---------------- k3: combine V-chunk partials ----------------
__global__ void combine_kernel(const float* __restrict__ pval,
                               const int* __restrict__ pidx,
                               int* __restrict__ outidx) {
    int row = blockIdx.x * blockDim.x + threadIdx.x;
    if (row >= NROWS) return;
    float best = -1e30f;
    int bidx = 0;
    // ascending chunk order + strict '>' keeps first max index globally
    for (int c = 0; c < VSPLITS; ++c) {
        float v = pval[c * NROWS + row];
        if (v > best) { best = v; bidx = pidx[c * NROWS + row]; }
    }
    outidx[row] = bidx;
}

// ---------------- k4: fused zero + one-hot write (1.048 GB) ----------------
__global__ void onehot_kernel(const int* __restrict__ idx, float4* __restrict__ out) {
    const unsigned V4 = VOCAB / 4;                 // 8000 float4 per row
    const unsigned total = (unsigned)NROWS * V4;   // 65,536,000
    unsigned i = blockIdx.x * blockDim.x + threadIdx.x;
    const unsigned stride = gridDim.x * blockDim.x;
    for (; i < total; i += stride) {
        unsigned row = i / V4;           // magic-mul division
        unsigned j = i - row * V4;
        int id = idx[row];
        int base = (int)(j * 4);
        float4 r;
        r.x = (id == base    ) ? 1.f : 0.f;
        r.y = (id == base + 1) ? 1.f : 0.f;
        r.z = (id == base + 2) ? 1.f : 0.f;
        r.w = (id == base + 3) ? 1.f : 0.f;
        out[i] = r;
    }
}

extern "C" void kernel_launch(void* const* d_in, const int* in_sizes, int n_in,
                              void* d_out, int out_size, void* d_ws, size_t ws_size,
                              hipStream_t stream) {
    const float* x = (const float*)d_in[0];   // [2,4096,64]
    const float* W = (const float*)d_in[1];   // [32000,64]
    float* out = (float*)d_out;

    char* ws = (char*)d_ws;
    float* invn = (float*)(ws);                          // 32000 f  = 128000 B
    float* pval = (float*)(ws + 128000);                 // 25*8192 f = 819200 B
    int*   pidx = (int*)  (ws + 128000 + 819200);        // 25*8192 i = 819200 B
    int*   fidx = (int*)  (ws + 128000 + 2 * 819200);    // 8192 i    = 32768 B

    wnorm_kernel<<<dim3((VOCAB + 255) / 256), dim3(256), 0, stream>>>(W, invn);

    argmax_partial_kernel<<<dim3(NROWS / ROWS_PER_BLOCK, VSPLITS), dim3(256), 0, stream>>>(
        x, W, invn, pval, pidx);

    combine_kernel<<<dim3((NROWS + 255) / 256), dim3(256), 0, stream>>>(pval, pidx, fidx);

    onehot_kernel<<<dim3(2048), dim3(256), 0, stream>>>(fidx, (float4*)out);
}